// Round 1
// baseline (628.549 us; speedup 1.0000x reference)
//
#include <hip/hip_runtime.h>
#include <stdint.h>

#define NB 8
#define NN 107136
#define TOTAL (NB * NN)
#define PRE 2048
#define POST 128
#define CAP 4096
#define NBINS 65536
#define SCORE_TH 0.05f

// ---------------- ws layout (bytes) ----------------
static constexpr size_t OFF_SCORES = 0;
static constexpr size_t SZ_SCORES  = (size_t)TOTAL * 4;            // 3,428,352
static constexpr size_t OFF_HIST   = OFF_SCORES + SZ_SCORES;
static constexpr size_t SZ_HIST    = (size_t)NB * NBINS * 4;       // 2,097,152
static constexpr size_t OFF_CNT    = OFF_HIST + SZ_HIST;           // 8 u32, pad 256
static constexpr size_t OFF_T      = OFF_CNT + 256;                // 8 u32, pad 256
static constexpr size_t OFF_CAND   = OFF_T + 256;
static constexpr size_t SZ_CAND    = (size_t)NB * CAP * 8;         // 262,144
static constexpr size_t OFF_SELS   = OFF_CAND + SZ_CAND;
static constexpr size_t OFF_SELI   = OFF_SELS + (size_t)NB * PRE * 4;
static constexpr size_t OFF_SELB   = OFF_SELI + (size_t)NB * PRE * 4;
static constexpr size_t OFF_SBB    = OFF_SELB + (size_t)NB * PRE * 7 * 4;
static constexpr size_t OFF_SAR    = OFF_SBB + (size_t)NB * PRE * 4 * 4;
static constexpr size_t OFF_MASK   = OFF_SAR + (size_t)NB * PRE * 4;
static constexpr size_t SZ_MASK    = (size_t)NB * PRE * 32 * 8;    // 4,194,304
// total ~10.9 MB

// ---------------- kernels ----------------

__global__ void k_zero(uint32_t* p, int nwords) {
    int g = blockIdx.x * 256 + threadIdx.x;
    if (g < nwords) p[g] = 0u;
}

// softmax score + histogram of 16-bit sortable-key prefix (valid only)
__global__ void k_scores(const float* __restrict__ cls, float* __restrict__ scores,
                         uint32_t* __restrict__ hist) {
    int g = blockIdx.x * 256 + threadIdx.x;
    if (g >= TOTAL) return;
    const float2 c = ((const float2*)cls)[g];
    float m  = fmaxf(c.x, c.y);
    float e0 = expf(__fsub_rn(c.x, m));
    float e1 = expf(__fsub_rn(c.y, m));
    float s  = __fdiv_rn(e1, __fadd_rn(e0, e1));
    scores[g] = s;
    if (s >= SCORE_TH) {
        uint32_t key = __float_as_uint(s) | 0x80000000u;   // s > 0 always
        int b = g / NN;
        atomicAdd(&hist[(size_t)b * NBINS + (key >> 16)], 1u);
    }
}

// per-batch: find threshold bin T s.t. count(bins >= T) >= PRE (suffix-sum scan)
__global__ void __launch_bounds__(1024) k_findT(const uint32_t* __restrict__ hist,
                                                uint32_t* __restrict__ Tout) {
    int b = blockIdx.x;
    const uint32_t* h = hist + (size_t)b * NBINS;
    __shared__ uint32_t part[1024];
    __shared__ uint32_t sfx[1024];
    int t = threadIdx.x;
    int base = t * 64;
    uint32_t s = 0;
    for (int i = 0; i < 64; i++) s += h[base + i];
    part[t] = s;
    sfx[t] = s;
    __syncthreads();
    // suffix sums over 1024 chunks (Hillis-Steele)
    for (int off = 1; off < 1024; off <<= 1) {
        uint32_t add = (t + off < 1024) ? sfx[t + off] : 0u;
        __syncthreads();
        sfx[t] += add;
        __syncthreads();
    }
    if (t == 0 && sfx[0] < PRE) Tout[b] = 0u;  // fewer than PRE valid: take all
    uint32_t above = sfx[t] - part[t];
    if (sfx[t] >= PRE && above < PRE) {
        uint32_t acc = above;
        uint32_t T = 0;
        for (int i = 63; i >= 0; i--) {
            acc += h[base + i];
            if (acc >= PRE) { T = (uint32_t)(base + i); break; }
        }
        Tout[b] = T;
    }
}

// compact candidates with key16 >= T into cand list as (key32<<32)|(~idx)
__global__ void k_compact(const float* __restrict__ scores, const uint32_t* __restrict__ T,
                          uint32_t* __restrict__ counts, uint64_t* __restrict__ cand) {
    int g = blockIdx.x * 256 + threadIdx.x;
    if (g >= TOTAL) return;
    float s = scores[g];
    if (s < SCORE_TH) return;
    int b = g / NN;
    int n = g - b * NN;
    uint32_t key = __float_as_uint(s) | 0x80000000u;
    if ((key >> 16) >= T[b]) {
        uint32_t slot = atomicAdd(&counts[b], 1u);
        if (slot < CAP)
            cand[(size_t)b * CAP + slot] =
                ((uint64_t)key << 32) | (uint64_t)(0xFFFFFFFFu - (uint32_t)n);
    }
}

// per-batch: bitonic sort CAP keys desc, decode top PRE boxes, standup + area
__global__ void __launch_bounds__(1024) k_sort_decode(
        const uint64_t* __restrict__ cand, const uint32_t* __restrict__ counts,
        const float* __restrict__ box_preds, const float* __restrict__ anchors,
        float* __restrict__ selS, uint32_t* __restrict__ selI,
        float* __restrict__ selB, float* __restrict__ selBB, float* __restrict__ selA) {
    int b = blockIdx.x;
    __shared__ uint64_t sh[CAP];   // 32 KiB
    int t = threadIdx.x;
    uint32_t cnt = counts[b]; if (cnt > CAP) cnt = CAP;
    for (int i = t; i < CAP; i += 1024)
        sh[i] = (i < (int)cnt) ? cand[(size_t)b * CAP + i] : 0ull;
    __syncthreads();
    for (int k = 2; k <= CAP; k <<= 1) {
        for (int j = k >> 1; j > 0; j >>= 1) {
            for (int i = t; i < CAP; i += 1024) {
                int ixj = i ^ j;
                if (ixj > i) {
                    uint64_t a = sh[i], c = sh[ixj];
                    bool desc = ((i & k) == 0);
                    bool sw = desc ? (a < c) : (a > c);
                    if (sw) { sh[i] = c; sh[ixj] = a; }
                }
            }
            __syncthreads();
        }
    }
    // top PRE entries: recover idx/score, decode, standup
    for (int kk = t; kk < PRE; kk += 1024) {
        uint64_t e = sh[kk];
        size_t o = (size_t)b * PRE + kk;
        if ((uint32_t)(e >> 32) == 0u) {
            selS[o] = -INFINITY; selI[o] = 0u;
            for (int c = 0; c < 7; c++) selB[o * 7 + c] = 0.f;
            for (int c = 0; c < 4; c++) selBB[o * 4 + c] = 0.f;
            selA[o] = 0.f;
            continue;
        }
        uint32_t key = (uint32_t)(e >> 32);
        uint32_t idx = 0xFFFFFFFFu - (uint32_t)(e & 0xFFFFFFFFull);
        float score = __uint_as_float(key & 0x7FFFFFFFu);
        const float* bp = box_preds + ((size_t)b * NN + idx) * 7;
        const float* an = anchors + ((size_t)b * NN + idx) * 7;
        float xa = an[0], ya = an[1], za = an[2], wa = an[3], la = an[4], ha = an[5], ra = an[6];
        float xt = bp[0], yt = bp[1], zt = bp[2], wt = bp[3], lt = bp[4], ht = bp[5], rt = bp[6];
        float za2  = __fadd_rn(za, __fmul_rn(ha, 0.5f));
        float diag = sqrtf(__fadd_rn(__fmul_rn(la, la), __fmul_rn(wa, wa)));
        float xg = __fadd_rn(__fmul_rn(xt, diag), xa);
        float yg = __fadd_rn(__fmul_rn(yt, diag), ya);
        float zg = __fadd_rn(__fmul_rn(zt, ha), za2);
        float lg = __fmul_rn(expf(lt), la);
        float wg = __fmul_rn(expf(wt), wa);
        float hg = __fmul_rn(expf(ht), ha);
        float rg = __fadd_rn(rt, ra);
        zg = __fsub_rn(zg, __fmul_rn(hg, 0.5f));
        selS[o] = score; selI[o] = idx;
        selB[o * 7 + 0] = xg; selB[o * 7 + 1] = yg; selB[o * 7 + 2] = zg;
        selB[o * 7 + 3] = wg; selB[o * 7 + 4] = lg; selB[o * 7 + 5] = hg;
        selB[o * 7 + 6] = rg;
        float cc = fabsf(cosf(rg)), ss = fabsf(sinf(rg));
        float hx = __fmul_rn(0.5f, __fadd_rn(__fmul_rn(wg, cc), __fmul_rn(lg, ss)));
        float hy = __fmul_rn(0.5f, __fadd_rn(__fmul_rn(wg, ss), __fmul_rn(lg, cc)));
        float x1 = __fsub_rn(xg, hx), y1 = __fsub_rn(yg, hy);
        float x2 = __fadd_rn(xg, hx), y2 = __fadd_rn(yg, hy);
        selBB[o * 4 + 0] = x1; selBB[o * 4 + 1] = y1;
        selBB[o * 4 + 2] = x2; selBB[o * 4 + 3] = y2;
        selA[o] = __fmul_rn(__fsub_rn(x2, x1), __fsub_rn(y2, y1));
    }
}

// suppression bitmask rows: bit j of word w of row i set iff iou(i,j)>0.5 && j>i
__global__ void __launch_bounds__(256) k_iou(const float* __restrict__ selBB,
                                             const float* __restrict__ selA,
                                             uint64_t* __restrict__ maskrows) {
    int b = blockIdx.y;
    int r0 = blockIdx.x * 64;
    __shared__ float sx1[PRE], sy1[PRE], sx2[PRE], sy2[PRE], sar[PRE];  // 40 KiB
    int t = threadIdx.x;
    for (int i = t; i < PRE; i += 256) {
        const float* p = selBB + ((size_t)b * PRE + i) * 4;
        sx1[i] = p[0]; sy1[i] = p[1]; sx2[i] = p[2]; sy2[i] = p[3];
        sar[i] = selA[(size_t)b * PRE + i];
    }
    __syncthreads();
    int w  = t & 31;           // word index (cols j in [w*64, w*64+64))
    int rl = t >> 5;           // 0..7
    int jbase = w * 64;
    float rx1[8], ry1[8], rx2[8], ry2[8], rar[8];
    int rows[8];
#pragma unroll
    for (int p = 0; p < 8; p++) {
        int i = r0 + rl * 8 + p;
        rows[p] = i;
        rx1[p] = sx1[i]; ry1[p] = sy1[i]; rx2[p] = sx2[i]; ry2[p] = sy2[i]; rar[p] = sar[i];
    }
    uint64_t bits[8] = {0, 0, 0, 0, 0, 0, 0, 0};
    for (int jj = 0; jj < 64; jj++) {
        int j = jbase + ((jj + w) & 63);   // swizzle to avoid 32-way bank conflict
        float xj1 = sx1[j], yj1 = sy1[j], xj2 = sx2[j], yj2 = sy2[j], aj = sar[j];
#pragma unroll
        for (int p = 0; p < 8; p++) {
            float ix = fmaxf(0.f, __fsub_rn(fminf(rx2[p], xj2), fmaxf(rx1[p], xj1)));
            float iy = fmaxf(0.f, __fsub_rn(fminf(ry2[p], yj2), fmaxf(ry1[p], yj1)));
            float inter = __fmul_rn(ix, iy);
            float den = fmaxf(__fsub_rn(__fadd_rn(rar[p], aj), inter), 1e-8f);
            float iou = __fdiv_rn(inter, den);
            if (iou > 0.5f && j > rows[p]) bits[p] |= (1ull << (j - jbase));
        }
    }
#pragma unroll
    for (int p = 0; p < 8; p++)
        maskrows[((size_t)b * PRE + rows[p]) * 32 + w] = bits[p];
}

// sequential greedy NMS (one wave) + finalize 128 outputs
__global__ void __launch_bounds__(128) k_nms_final(
        const uint64_t* __restrict__ maskrows, const float* __restrict__ selS,
        const uint32_t* __restrict__ selI, const float* __restrict__ selB,
        const uint32_t* __restrict__ counts, const float* __restrict__ dir_preds,
        float* __restrict__ out) {
    int b = blockIdx.x;
    __shared__ int keptIdx[POST];
    __shared__ int keptCount;
    int t = threadIdx.x;
    int Mv = (int)counts[b]; if (Mv > PRE) Mv = PRE;
    if (t < 64) {
        uint64_t removed = 0ull;
        int kc = 0;
        const uint64_t* mb = maskrows + (size_t)b * PRE * 32;
        for (int i = 0; i < PRE && kc < POST; i++) {
            if (i >= Mv) break;                       // remaining are -inf (invalid)
            uint64_t mrow = (t < 32) ? mb[(size_t)i * 32 + t] : 0ull;
            uint64_t rw = __shfl(removed, i >> 6);
            bool sup = (rw >> (i & 63)) & 1ull;
            if (!sup) {
                if (t == 0) keptIdx[kc] = i;
                kc++;
                removed |= mrow;
            }
        }
        if (t == 0) keptCount = kc;
    }
    __syncthreads();
    int kc = keptCount;
    size_t ob = (size_t)b * POST + t;
    float box[7] = {0.f, 0.f, 0.f, 0.f, 0.f, 0.f, 0.f};
    float sc = 0.f, mk = 0.f;
    if (t < kc) {
        int i = keptIdx[t];
        size_t o = (size_t)b * PRE + i;
        float s = selS[o];
        uint32_t idx = selI[o];
        const float* bx = selB + o * 7;
        float d0 = dir_preds[((size_t)b * NN + idx) * 2 + 0];
        float d1 = dir_preds[((size_t)b * NN + idx) * 2 + 1];
        float label = (d1 > d0) ? 1.0f : 0.0f;
        const float period = 3.14159265358979323846f;   // float32(pi)
        float r = bx[6];
        float dir_rot = __fsub_rn(r, __fmul_rn(floorf(__fdiv_rn(r, period)), period));
        float nr = __fadd_rn(dir_rot, __fmul_rn(period, label));
        float x = bx[0], y = bx[1], z = bx[2];
        bool in_range = (x >= 0.0f) && (y >= -39.68f) && (z >= -5.0f) &&
                        (x <= 69.12f) && (y <= 39.68f) && (z <= 5.0f);
        if (in_range) {
            box[0] = x; box[1] = y; box[2] = z;
            box[3] = bx[3]; box[4] = bx[4]; box[5] = bx[5]; box[6] = nr;
            sc = s; mk = 1.f;
        }
    }
    float* out_b = out;                // (8,128,7)
    float* out_s = out + 7168;         // (8,128)
    float* out_l = out + 8192;         // (8,128) labels, all zero
    float* out_m = out + 9216;         // (8,128) mask
    for (int c = 0; c < 7; c++) out_b[ob * 7 + c] = box[c];
    out_s[ob] = sc;
    out_l[ob] = 0.f;
    out_m[ob] = mk;
}

extern "C" void kernel_launch(void* const* d_in, const int* in_sizes, int n_in,
                              void* d_out, int out_size, void* d_ws, size_t ws_size,
                              hipStream_t stream) {
    const float* box_preds = (const float*)d_in[0];
    const float* cls_preds = (const float*)d_in[1];
    const float* dir_preds = (const float*)d_in[2];
    const float* anchors   = (const float*)d_in[3];
    float* out = (float*)d_out;
    char* ws = (char*)d_ws;

    float*    scores = (float*)(ws + OFF_SCORES);
    uint32_t* hist   = (uint32_t*)(ws + OFF_HIST);
    uint32_t* counts = (uint32_t*)(ws + OFF_CNT);
    uint32_t* T      = (uint32_t*)(ws + OFF_T);
    uint64_t* cand   = (uint64_t*)(ws + OFF_CAND);
    float*    selS   = (float*)(ws + OFF_SELS);
    uint32_t* selI   = (uint32_t*)(ws + OFF_SELI);
    float*    selB   = (float*)(ws + OFF_SELB);
    float*    selBB  = (float*)(ws + OFF_SBB);
    float*    selA   = (float*)(ws + OFF_SAR);
    uint64_t* maskrows = (uint64_t*)(ws + OFF_MASK);

    int zwords = (int)((SZ_HIST + 256) / 4);   // hist + counts
    k_zero<<<(zwords + 255) / 256, 256, 0, stream>>>(hist, zwords);

    int gridBN = (TOTAL + 255) / 256;
    k_scores<<<gridBN, 256, 0, stream>>>(cls_preds, scores, hist);
    k_findT<<<NB, 1024, 0, stream>>>(hist, T);
    k_compact<<<gridBN, 256, 0, stream>>>(scores, T, counts, cand);
    k_sort_decode<<<NB, 1024, 0, stream>>>(cand, counts, box_preds, anchors,
                                           selS, selI, selB, selBB, selA);
    dim3 gIou(PRE / 64, NB);
    k_iou<<<gIou, 256, 0, stream>>>(selBB, selA, maskrows);
    k_nms_final<<<NB, 128, 0, stream>>>(maskrows, selS, selI, selB, counts,
                                        dir_preds, out);
}

// Round 2
// 265.570 us; speedup vs baseline: 2.3668x; 2.3668x over previous
//
#include <hip/hip_runtime.h>
#include <stdint.h>

#define NB 8
#define NN 107136
#define TOTAL (NB * NN)
#define PRE 2048
#define POST 128
#define CAP 4096
#define HBINS 128          // 16-bit key bins restricted to s in [0.5, 1)
#define KEYBASE 0xBF00u
#define SCORE_TH 0.05f
#define NSEG 16            // hist blocks per batch
#define SEGLEN (NN / NSEG) // 6696

// ---------------- ws layout (bytes) ----------------
static constexpr size_t OFF_SCORES = 0;
static constexpr size_t SZ_SCORES  = (size_t)TOTAL * 4;            // 3,428,352
static constexpr size_t OFF_HIST   = OFF_SCORES + SZ_SCORES;
static constexpr size_t SZ_HIST    = (size_t)NB * HBINS * 4;       // 4096
static constexpr size_t OFF_CNT    = OFF_HIST + SZ_HIST;           // 8 x 64 u32 (padded 256B apart)
static constexpr size_t SZ_CNT     = (size_t)NB * 64 * 4;          // 2048
static constexpr size_t OFF_T      = OFF_CNT + SZ_CNT;             // 8 u32, pad 256
static constexpr size_t OFF_CAND   = OFF_T + 256;
static constexpr size_t SZ_CAND    = (size_t)NB * CAP * 8;         // 262,144
static constexpr size_t OFF_SELS   = OFF_CAND + SZ_CAND;
static constexpr size_t OFF_SELI   = OFF_SELS + (size_t)NB * PRE * 4;
static constexpr size_t OFF_SELB   = OFF_SELI + (size_t)NB * PRE * 4;
static constexpr size_t OFF_SBB    = OFF_SELB + (size_t)NB * PRE * 7 * 4;
static constexpr size_t OFF_SAR    = OFF_SBB + (size_t)NB * PRE * 4 * 4;
static constexpr size_t OFF_MASK   = OFF_SAR + (size_t)NB * PRE * 4;
static constexpr size_t SZ_MASK    = (size_t)NB * PRE * 32 * 8;    // 4,194,304

// ---------------- kernels ----------------

__global__ void k_zero(uint32_t* p, int nwords) {
    int g = blockIdx.x * 256 + threadIdx.x;
    if (g < nwords) p[g] = 0u;
}

// softmax scores, pure streaming, 2 elements/thread (float4 in, float2 out)
__global__ void k_scores(const float* __restrict__ cls, float* __restrict__ scores) {
    int g2 = blockIdx.x * 256 + threadIdx.x;          // 428,544 pairs, grid exact
    const float4 c = ((const float4*)cls)[g2];
    float m0  = fmaxf(c.x, c.y);
    float s0  = __fdiv_rn(expf(__fsub_rn(c.y, m0)),
                          __fadd_rn(expf(__fsub_rn(c.x, m0)), expf(__fsub_rn(c.y, m0))));
    float m1  = fmaxf(c.z, c.w);
    float s1  = __fdiv_rn(expf(__fsub_rn(c.w, m1)),
                          __fadd_rn(expf(__fsub_rn(c.z, m1)), expf(__fsub_rn(c.w, m1))));
    ((float2*)scores)[g2] = make_float2(s0, s1);
}

// per-batch 128-bin histogram of 16-bit key prefix, s in [0.5,1), LDS-privatized
__global__ void __launch_bounds__(256) k_hist(const float* __restrict__ scores,
                                              uint32_t* __restrict__ hist) {
    int b   = blockIdx.x / NSEG;
    int seg = blockIdx.x % NSEG;
    __shared__ uint32_t lh[HBINS];
    int t = threadIdx.x;
    if (t < HBINS) lh[t] = 0u;
    __syncthreads();
    const float* s = scores + (size_t)b * NN;
    int end = (seg + 1) * SEGLEN;
    for (int i = seg * SEGLEN + t; i < end; i += 256) {
        float v = s[i];
        if (v >= 0.5f) {
            uint32_t key16 = (__float_as_uint(v) >> 16) | 0x8000u;
            uint32_t bin = key16 - KEYBASE;
            if (bin > 127u) bin = 127u;   // s==1.0 rounding guard
            atomicAdd(&lh[bin], 1u);
        }
    }
    __syncthreads();
    if (t < HBINS && lh[t]) atomicAdd(&hist[b * HBINS + t], lh[t]);
}

// per-batch: largest bin with suffix-count >= PRE (one wave per batch)
__global__ void __launch_bounds__(64) k_findT(const uint32_t* __restrict__ hist,
                                              uint32_t* __restrict__ Tout) {
    int b = blockIdx.x, t = threadIdx.x;
    const uint32_t* h = hist + b * HBINS;
    uint32_t h0 = h[2 * t], h1 = h[2 * t + 1];
    uint32_t v = h0 + h1;                      // suffix starting at bin 2t (within pair)
    for (int off = 1; off < 64; off <<= 1) {
        uint32_t u = __shfl_down(v, off);
        if (t + off >= 64) u = 0u;
        v += u;
    }
    uint32_t total = __shfl(v, 0);
    int c = -1;
    if (v - h0 >= PRE) c = 2 * t + 1;
    else if (v >= PRE) c = 2 * t;
    for (int off = 32; off > 0; off >>= 1) c = max(c, __shfl_xor(c, off));
    if (t == 0) Tout[b] = (total >= PRE && c >= 0) ? (KEYBASE + (uint32_t)c) : 0u;
}

// compact candidates with key16 >= T; block-aggregated slot reservation
__global__ void __launch_bounds__(256) k_compact(const float* __restrict__ scores,
                                                 const uint32_t* __restrict__ T,
                                                 uint32_t* __restrict__ counts,
                                                 uint64_t* __restrict__ cand) {
    int g = blockIdx.x * 256 + threadIdx.x;
    int lane = threadIdx.x & 63, wid = threadIdx.x >> 6;
    int b0 = (blockIdx.x * 256) / NN;             // first batch this block touches
    bool pass = (g < TOTAL);
    int b = 0; uint32_t key = 0;
    if (pass) {
        float s = scores[g];
        b = g / NN;
        key = __float_as_uint(s) | 0x80000000u;
        pass = (s >= SCORE_TH) && ((key >> 16) >= T[b]);
    }
    uint64_t bal = __ballot(pass);
    uint32_t wcnt = (uint32_t)__popcll(bal);
    uint32_t wpre = (uint32_t)__popcll(bal & ((1ull << lane) - 1ull));
    __shared__ uint32_t lcnt[2];
    __shared__ uint32_t gbase[2];
    __shared__ uint32_t wbase[4];
    if (threadIdx.x < 2) lcnt[threadIdx.x] = 0u;
    __syncthreads();
    int wb = (blockIdx.x * 256 + wid * 64) / NN;  // wave's batch (NN%64==0 -> uniform)
    if (lane == 0 && wcnt) wbase[wid] = atomicAdd(&lcnt[wb - b0], wcnt);
    __syncthreads();
    if (threadIdx.x < 2 && lcnt[threadIdx.x])
        gbase[threadIdx.x] = atomicAdd(&counts[(size_t)(b0 + threadIdx.x) * 64], lcnt[threadIdx.x]);
    __syncthreads();
    if (pass) {
        int n = g - b * NN;
        uint32_t slot = gbase[b - b0] + wbase[wid] + wpre;
        if (slot < CAP)
            cand[(size_t)b * CAP + slot] =
                ((uint64_t)key << 32) | (uint64_t)(0xFFFFFFFFu - (uint32_t)n);
    }
}

// per-batch: bitonic sort CAP keys desc, decode top PRE boxes, standup + area
__global__ void __launch_bounds__(1024) k_sort_decode(
        const uint64_t* __restrict__ cand, const uint32_t* __restrict__ counts,
        const float* __restrict__ box_preds, const float* __restrict__ anchors,
        float* __restrict__ selS, uint32_t* __restrict__ selI,
        float* __restrict__ selB, float* __restrict__ selBB, float* __restrict__ selA) {
    int b = blockIdx.x;
    __shared__ uint64_t sh[CAP];   // 32 KiB
    int t = threadIdx.x;
    uint32_t cnt = counts[(size_t)b * 64]; if (cnt > CAP) cnt = CAP;
    for (int i = t; i < CAP; i += 1024)
        sh[i] = (i < (int)cnt) ? cand[(size_t)b * CAP + i] : 0ull;
    __syncthreads();
    for (int k = 2; k <= CAP; k <<= 1) {
        for (int j = k >> 1; j > 0; j >>= 1) {
            for (int i = t; i < CAP; i += 1024) {
                int ixj = i ^ j;
                if (ixj > i) {
                    uint64_t a = sh[i], c = sh[ixj];
                    bool desc = ((i & k) == 0);
                    bool sw = desc ? (a < c) : (a > c);
                    if (sw) { sh[i] = c; sh[ixj] = a; }
                }
            }
            __syncthreads();
        }
    }
    for (int kk = t; kk < PRE; kk += 1024) {
        uint64_t e = sh[kk];
        size_t o = (size_t)b * PRE + kk;
        if ((uint32_t)(e >> 32) == 0u) {
            selS[o] = -INFINITY; selI[o] = 0u;
            for (int c = 0; c < 7; c++) selB[o * 7 + c] = 0.f;
            for (int c = 0; c < 4; c++) selBB[o * 4 + c] = 0.f;
            selA[o] = 0.f;
            continue;
        }
        uint32_t key = (uint32_t)(e >> 32);
        uint32_t idx = 0xFFFFFFFFu - (uint32_t)(e & 0xFFFFFFFFull);
        float score = __uint_as_float(key & 0x7FFFFFFFu);
        const float* bp = box_preds + ((size_t)b * NN + idx) * 7;
        const float* an = anchors + ((size_t)b * NN + idx) * 7;
        float xa = an[0], ya = an[1], za = an[2], wa = an[3], la = an[4], ha = an[5], ra = an[6];
        float xt = bp[0], yt = bp[1], zt = bp[2], wt = bp[3], lt = bp[4], ht = bp[5], rt = bp[6];
        float za2  = __fadd_rn(za, __fmul_rn(ha, 0.5f));
        float diag = sqrtf(__fadd_rn(__fmul_rn(la, la), __fmul_rn(wa, wa)));
        float xg = __fadd_rn(__fmul_rn(xt, diag), xa);
        float yg = __fadd_rn(__fmul_rn(yt, diag), ya);
        float zg = __fadd_rn(__fmul_rn(zt, ha), za2);
        float lg = __fmul_rn(expf(lt), la);
        float wg = __fmul_rn(expf(wt), wa);
        float hg = __fmul_rn(expf(ht), ha);
        float rg = __fadd_rn(rt, ra);
        zg = __fsub_rn(zg, __fmul_rn(hg, 0.5f));
        selS[o] = score; selI[o] = idx;
        selB[o * 7 + 0] = xg; selB[o * 7 + 1] = yg; selB[o * 7 + 2] = zg;
        selB[o * 7 + 3] = wg; selB[o * 7 + 4] = lg; selB[o * 7 + 5] = hg;
        selB[o * 7 + 6] = rg;
        float cc = fabsf(cosf(rg)), ss = fabsf(sinf(rg));
        float hx = __fmul_rn(0.5f, __fadd_rn(__fmul_rn(wg, cc), __fmul_rn(lg, ss)));
        float hy = __fmul_rn(0.5f, __fadd_rn(__fmul_rn(wg, ss), __fmul_rn(lg, cc)));
        float x1 = __fsub_rn(xg, hx), y1 = __fsub_rn(yg, hy);
        float x2 = __fadd_rn(xg, hx), y2 = __fadd_rn(yg, hy);
        selBB[o * 4 + 0] = x1; selBB[o * 4 + 1] = y1;
        selBB[o * 4 + 2] = x2; selBB[o * 4 + 3] = y2;
        selA[o] = __fmul_rn(__fsub_rn(x2, x1), __fsub_rn(y2, y1));
    }
}

// suppression bitmask rows: bit j of word w of row i set iff iou(i,j)>0.5 && j>i
__global__ void __launch_bounds__(256) k_iou(const float* __restrict__ selBB,
                                             const float* __restrict__ selA,
                                             uint64_t* __restrict__ maskrows) {
    int b = blockIdx.y;
    int r0 = blockIdx.x * 64;
    __shared__ float sx1[PRE], sy1[PRE], sx2[PRE], sy2[PRE], sar[PRE];  // 40 KiB
    int t = threadIdx.x;
    for (int i = t; i < PRE; i += 256) {
        const float* p = selBB + ((size_t)b * PRE + i) * 4;
        sx1[i] = p[0]; sy1[i] = p[1]; sx2[i] = p[2]; sy2[i] = p[3];
        sar[i] = selA[(size_t)b * PRE + i];
    }
    __syncthreads();
    int w  = t & 31;
    int rl = t >> 5;
    int jbase = w * 64;
    float rx1[8], ry1[8], rx2[8], ry2[8], rar[8];
    int rows[8];
#pragma unroll
    for (int p = 0; p < 8; p++) {
        int i = r0 + rl * 8 + p;
        rows[p] = i;
        rx1[p] = sx1[i]; ry1[p] = sy1[i]; rx2[p] = sx2[i]; ry2[p] = sy2[i]; rar[p] = sar[i];
    }
    uint64_t bits[8] = {0, 0, 0, 0, 0, 0, 0, 0};
    for (int jj = 0; jj < 64; jj++) {
        int j = jbase + ((jj + w) & 63);
        float xj1 = sx1[j], yj1 = sy1[j], xj2 = sx2[j], yj2 = sy2[j], aj = sar[j];
#pragma unroll
        for (int p = 0; p < 8; p++) {
            float ix = fmaxf(0.f, __fsub_rn(fminf(rx2[p], xj2), fmaxf(rx1[p], xj1)));
            float iy = fmaxf(0.f, __fsub_rn(fminf(ry2[p], yj2), fmaxf(ry1[p], yj1)));
            float inter = __fmul_rn(ix, iy);
            float den = fmaxf(__fsub_rn(__fadd_rn(rar[p], aj), inter), 1e-8f);
            float iou = __fdiv_rn(inter, den);
            if (iou > 0.5f && j > rows[p]) bits[p] |= (1ull << (j - jbase));
        }
    }
#pragma unroll
    for (int p = 0; p < 8; p++)
        maskrows[((size_t)b * PRE + rows[p]) * 32 + w] = bits[p];
}

// sequential greedy NMS (one wave) + finalize 128 outputs
__global__ void __launch_bounds__(128) k_nms_final(
        const uint64_t* __restrict__ maskrows, const float* __restrict__ selS,
        const uint32_t* __restrict__ selI, const float* __restrict__ selB,
        const uint32_t* __restrict__ counts, const float* __restrict__ dir_preds,
        float* __restrict__ out) {
    int b = blockIdx.x;
    __shared__ int keptIdx[POST];
    __shared__ int keptCount;
    int t = threadIdx.x;
    int Mv = (int)counts[(size_t)b * 64]; if (Mv > PRE) Mv = PRE;
    if (t < 64) {
        uint64_t removed = 0ull;
        int kc = 0;
        const uint64_t* mb = maskrows + (size_t)b * PRE * 32;
        for (int i = 0; i < PRE && kc < POST; i++) {
            if (i >= Mv) break;
            uint64_t mrow = (t < 32) ? mb[(size_t)i * 32 + t] : 0ull;
            uint64_t rw = __shfl(removed, i >> 6);
            bool sup = (rw >> (i & 63)) & 1ull;
            if (!sup) {
                if (t == 0) keptIdx[kc] = i;
                kc++;
                removed |= mrow;
            }
        }
        if (t == 0) keptCount = kc;
    }
    __syncthreads();
    int kc = keptCount;
    size_t ob = (size_t)b * POST + t;
    float box[7] = {0.f, 0.f, 0.f, 0.f, 0.f, 0.f, 0.f};
    float sc = 0.f, mk = 0.f;
    if (t < kc) {
        int i = keptIdx[t];
        size_t o = (size_t)b * PRE + i;
        float s = selS[o];
        uint32_t idx = selI[o];
        const float* bx = selB + o * 7;
        float d0 = dir_preds[((size_t)b * NN + idx) * 2 + 0];
        float d1 = dir_preds[((size_t)b * NN + idx) * 2 + 1];
        float label = (d1 > d0) ? 1.0f : 0.0f;
        const float period = 3.14159265358979323846f;
        float r = bx[6];
        float dir_rot = __fsub_rn(r, __fmul_rn(floorf(__fdiv_rn(r, period)), period));
        float nr = __fadd_rn(dir_rot, __fmul_rn(period, label));
        float x = bx[0], y = bx[1], z = bx[2];
        bool in_range = (x >= 0.0f) && (y >= -39.68f) && (z >= -5.0f) &&
                        (x <= 69.12f) && (y <= 39.68f) && (z <= 5.0f);
        if (in_range) {
            box[0] = x; box[1] = y; box[2] = z;
            box[3] = bx[3]; box[4] = bx[4]; box[5] = bx[5]; box[6] = nr;
            sc = s; mk = 1.f;
        }
    }
    float* out_b = out;
    float* out_s = out + 7168;
    float* out_l = out + 8192;
    float* out_m = out + 9216;
    for (int c = 0; c < 7; c++) out_b[ob * 7 + c] = box[c];
    out_s[ob] = sc;
    out_l[ob] = 0.f;
    out_m[ob] = mk;
}

extern "C" void kernel_launch(void* const* d_in, const int* in_sizes, int n_in,
                              void* d_out, int out_size, void* d_ws, size_t ws_size,
                              hipStream_t stream) {
    const float* box_preds = (const float*)d_in[0];
    const float* cls_preds = (const float*)d_in[1];
    const float* dir_preds = (const float*)d_in[2];
    const float* anchors   = (const float*)d_in[3];
    float* out = (float*)d_out;
    char* ws = (char*)d_ws;

    float*    scores = (float*)(ws + OFF_SCORES);
    uint32_t* hist   = (uint32_t*)(ws + OFF_HIST);
    uint32_t* counts = (uint32_t*)(ws + OFF_CNT);
    uint32_t* T      = (uint32_t*)(ws + OFF_T);
    uint64_t* cand   = (uint64_t*)(ws + OFF_CAND);
    float*    selS   = (float*)(ws + OFF_SELS);
    uint32_t* selI   = (uint32_t*)(ws + OFF_SELI);
    float*    selB   = (float*)(ws + OFF_SELB);
    float*    selBB  = (float*)(ws + OFF_SBB);
    float*    selA   = (float*)(ws + OFF_SAR);
    uint64_t* maskrows = (uint64_t*)(ws + OFF_MASK);

    int zwords = (int)((SZ_HIST + SZ_CNT + 256) / 4);   // hist + counts + T
    k_zero<<<(zwords + 255) / 256, 256, 0, stream>>>(hist, zwords);

    k_scores<<<TOTAL / 512, 256, 0, stream>>>(cls_preds, scores);
    k_hist<<<NB * NSEG, 256, 0, stream>>>(scores, hist);
    k_findT<<<NB, 64, 0, stream>>>(hist, T);
    int gridBN = (TOTAL + 255) / 256;
    k_compact<<<gridBN, 256, 0, stream>>>(scores, T, counts, cand);
    k_sort_decode<<<NB, 1024, 0, stream>>>(cand, counts, box_preds, anchors,
                                           selS, selI, selB, selBB, selA);
    dim3 gIou(PRE / 64, NB);
    k_iou<<<gIou, 256, 0, stream>>>(selBB, selA, maskrows);
    k_nms_final<<<NB, 128, 0, stream>>>(maskrows, selS, selI, selB, counts,
                                        dir_preds, out);
}

// Round 3
// 222.198 us; speedup vs baseline: 2.8288x; 1.1952x over previous
//
#include <hip/hip_runtime.h>
#include <stdint.h>

#define NB 8
#define NN 107136
#define TOTAL (NB * NN)
#define NPAIR (NN / 2)       // 53568
#define PRE 2048
#define POST 128
#define CAP 4096
#define HBINS 128            // 16-bit key bins restricted to s in [0.5, 1)
#define KEYBASE 0xBF00u
#define SCORE_TH 0.05f
#define SH_BPB 53            // score/hist blocks per batch (53*1024 >= 53568 pairs)

// ---------------- ws layout (bytes) ----------------
static constexpr size_t OFF_SCORES = 0;
static constexpr size_t SZ_SCORES  = (size_t)TOTAL * 4;
static constexpr size_t OFF_HIST   = OFF_SCORES + SZ_SCORES;
static constexpr size_t SZ_HIST    = (size_t)NB * HBINS * 4;       // 4096
static constexpr size_t OFF_CNT    = OFF_HIST + SZ_HIST;           // 8 x 64 u32 (256B apart)
static constexpr size_t SZ_CNT     = (size_t)NB * 64 * 4;          // 2048
static constexpr size_t OFF_T      = OFF_CNT + SZ_CNT;             // 8 u32, pad 256
static constexpr size_t OFF_CAND   = OFF_T + 256;
static constexpr size_t SZ_CAND    = (size_t)NB * CAP * 8;         // 262,144
static constexpr size_t OFF_SELS   = OFF_CAND + SZ_CAND;
static constexpr size_t OFF_SELI   = OFF_SELS + (size_t)NB * PRE * 4;
static constexpr size_t OFF_SELB   = OFF_SELI + (size_t)NB * PRE * 4;
static constexpr size_t OFF_SBB    = OFF_SELB + (size_t)NB * PRE * 7 * 4;
static constexpr size_t OFF_SAR    = OFF_SBB + (size_t)NB * PRE * 4 * 4;
static constexpr size_t OFF_MASK   = OFF_SAR + (size_t)NB * PRE * 4;
static constexpr size_t SZ_MASK    = (size_t)NB * PRE * 32 * 8;    // 4,194,304

// ---------------- kernels ----------------

__global__ void k_zero(uint32_t* p, int nwords) {
    int g = blockIdx.x * 256 + threadIdx.x;
    if (g < nwords) p[g] = 0u;
}

// fused softmax scores + 128-bin LDS histogram (s in [0.5,1) key prefix)
__global__ void __launch_bounds__(256) k_scoreshist(const float* __restrict__ cls,
                                                    float* __restrict__ scores,
                                                    uint32_t* __restrict__ hist) {
    int b = blockIdx.y;
    __shared__ uint32_t lh[HBINS];
    int t = threadIdx.x;
    if (t < HBINS) lh[t] = 0u;
    __syncthreads();
    const float4* cp = (const float4*)cls + (size_t)b * NPAIR;
    float2* sp = (float2*)scores + (size_t)b * NPAIR;
#pragma unroll
    for (int k = 0; k < 4; k++) {
        int p = blockIdx.x * 1024 + k * 256 + t;
        if (p < NPAIR) {
            float4 c = cp[p];
            float m0 = fmaxf(c.x, c.y);
            float s0 = __fdiv_rn(expf(__fsub_rn(c.y, m0)),
                                 __fadd_rn(expf(__fsub_rn(c.x, m0)), expf(__fsub_rn(c.y, m0))));
            float m1 = fmaxf(c.z, c.w);
            float s1 = __fdiv_rn(expf(__fsub_rn(c.w, m1)),
                                 __fadd_rn(expf(__fsub_rn(c.z, m1)), expf(__fsub_rn(c.w, m1))));
            sp[p] = make_float2(s0, s1);
            if (s0 >= 0.5f) {
                uint32_t bin = ((__float_as_uint(s0) >> 16) | 0x8000u) - KEYBASE;
                if (bin > 127u) bin = 127u;
                atomicAdd(&lh[bin], 1u);
            }
            if (s1 >= 0.5f) {
                uint32_t bin = ((__float_as_uint(s1) >> 16) | 0x8000u) - KEYBASE;
                if (bin > 127u) bin = 127u;
                atomicAdd(&lh[bin], 1u);
            }
        }
    }
    __syncthreads();
    if (t < HBINS && lh[t]) atomicAdd(&hist[b * HBINS + t], lh[t]);
}

// per-batch: largest bin with suffix-count >= PRE (one wave per batch)
__global__ void __launch_bounds__(64) k_findT(const uint32_t* __restrict__ hist,
                                              uint32_t* __restrict__ Tout) {
    int b = blockIdx.x, t = threadIdx.x;
    const uint32_t* h = hist + b * HBINS;
    uint32_t h0 = h[2 * t], h1 = h[2 * t + 1];
    uint32_t v = h0 + h1;
    for (int off = 1; off < 64; off <<= 1) {
        uint32_t u = __shfl_down(v, off);
        if (t + off >= 64) u = 0u;
        v += u;
    }
    uint32_t total = __shfl(v, 0);
    int c = -1;
    if (v - h0 >= PRE) c = 2 * t + 1;
    else if (v >= PRE) c = 2 * t;
    for (int off = 32; off > 0; off >>= 1) c = max(c, __shfl_xor(c, off));
    if (t == 0) Tout[b] = (total >= PRE && c >= 0) ? (KEYBASE + (uint32_t)c) : 0u;
}

// compact candidates with key16 >= T; block-aggregated slot reservation; 2 elems/thread
__global__ void __launch_bounds__(256) k_compact(const float* __restrict__ scores,
                                                 const uint32_t* __restrict__ T,
                                                 uint32_t* __restrict__ counts,
                                                 uint64_t* __restrict__ cand) {
    int g2 = blockIdx.x * 256 + threadIdx.x;      // pair index; grid exact (428544/256)
    int lane = threadIdx.x & 63, wid = threadIdx.x >> 6;
    float2 sv = ((const float2*)scores)[g2];
    int e0 = 2 * g2;
    int b = e0 / NN;                              // wave-uniform (NN % 128 == 0)
    uint32_t Tb = T[b];
    uint32_t key0 = __float_as_uint(sv.x) | 0x80000000u;
    uint32_t key1 = __float_as_uint(sv.y) | 0x80000000u;
    bool p0 = (sv.x >= SCORE_TH) && ((key0 >> 16) >= Tb);
    bool p1 = (sv.y >= SCORE_TH) && ((key1 >> 16) >= Tb);
    uint64_t bal0 = __ballot(p0), bal1 = __ballot(p1);
    uint32_t n0 = (uint32_t)__popcll(bal0);
    uint32_t wcnt = n0 + (uint32_t)__popcll(bal1);
    uint64_t below = (lane == 63) ? ~0ull >> 1 : ((1ull << lane) - 1ull);
    below = (1ull << lane) - 1ull;  // lane<64; 1ull<<63 ok, lane==63 -> low 63 bits
    uint32_t off0 = (uint32_t)__popcll(bal0 & below);
    uint32_t off1 = n0 + (uint32_t)__popcll(bal1 & below);
    __shared__ uint32_t lcnt[2];
    __shared__ uint32_t gbase[2];
    __shared__ uint32_t wbase[4];
    int b0 = (blockIdx.x * 512) / NN;
    if (threadIdx.x < 2) lcnt[threadIdx.x] = 0u;
    __syncthreads();
    if (lane == 0 && wcnt) wbase[wid] = atomicAdd(&lcnt[b - b0], wcnt);
    __syncthreads();
    if (threadIdx.x < 2 && lcnt[threadIdx.x])
        gbase[threadIdx.x] = atomicAdd(&counts[(size_t)(b0 + threadIdx.x) * 64], lcnt[threadIdx.x]);
    __syncthreads();
    if (p0 | p1) {
        uint32_t base = gbase[b - b0] + wbase[wid];
        if (p0) {
            uint32_t slot = base + off0;
            if (slot < CAP)
                cand[(size_t)b * CAP + slot] =
                    ((uint64_t)key0 << 32) | (uint64_t)(0xFFFFFFFFu - (uint32_t)(e0 - b * NN));
        }
        if (p1) {
            uint32_t slot = base + off1;
            if (slot < CAP)
                cand[(size_t)b * CAP + slot] =
                    ((uint64_t)key1 << 32) | (uint64_t)(0xFFFFFFFFu - (uint32_t)(e0 + 1 - b * NN));
        }
    }
}

// rank-based selection (replaces bitonic sort): rank = #{keys > mine}; decode at sel[rank]
__global__ void __launch_bounds__(256) k_rank_decode(
        const uint64_t* __restrict__ cand, const uint32_t* __restrict__ counts,
        const float* __restrict__ box_preds, const float* __restrict__ anchors,
        float* __restrict__ selS, uint32_t* __restrict__ selI,
        float* __restrict__ selB, float* __restrict__ selBB, float* __restrict__ selA) {
    int b = blockIdx.y;
    int i = blockIdx.x * 256 + threadIdx.x;
    int m = (int)counts[(size_t)b * 64]; if (m > CAP) m = CAP;
    const uint64_t* cb = cand + (size_t)b * CAP;
    uint64_t mykey = (i < m) ? cb[i] : 0ull;
    __shared__ uint64_t tile[512];
    int rank = 0;
    for (int base = 0; base < m; base += 512) {
        int nt = min(512, m - base);
        for (int j = threadIdx.x; j < nt; j += 256) tile[j] = cb[base + j];
        __syncthreads();
        if (i < m) {
            int j = 0;
            for (; j + 8 <= nt; j += 8) {
#pragma unroll
                for (int u = 0; u < 8; u++) rank += (tile[j + u] > mykey) ? 1 : 0;
            }
            for (; j < nt; j++) rank += (tile[j] > mykey) ? 1 : 0;
        }
        __syncthreads();
    }
    if (i >= m || rank >= PRE) return;
    size_t o = (size_t)b * PRE + rank;
    uint32_t key = (uint32_t)(mykey >> 32);
    uint32_t idx = 0xFFFFFFFFu - (uint32_t)(mykey & 0xFFFFFFFFull);
    float score = __uint_as_float(key & 0x7FFFFFFFu);
    const float* bp = box_preds + ((size_t)b * NN + idx) * 7;
    const float* an = anchors + ((size_t)b * NN + idx) * 7;
    float xa = an[0], ya = an[1], za = an[2], wa = an[3], la = an[4], ha = an[5], ra = an[6];
    float xt = bp[0], yt = bp[1], zt = bp[2], wt = bp[3], lt = bp[4], ht = bp[5], rt = bp[6];
    float za2  = __fadd_rn(za, __fmul_rn(ha, 0.5f));
    float diag = sqrtf(__fadd_rn(__fmul_rn(la, la), __fmul_rn(wa, wa)));
    float xg = __fadd_rn(__fmul_rn(xt, diag), xa);
    float yg = __fadd_rn(__fmul_rn(yt, diag), ya);
    float zg = __fadd_rn(__fmul_rn(zt, ha), za2);
    float lg = __fmul_rn(expf(lt), la);
    float wg = __fmul_rn(expf(wt), wa);
    float hg = __fmul_rn(expf(ht), ha);
    float rg = __fadd_rn(rt, ra);
    zg = __fsub_rn(zg, __fmul_rn(hg, 0.5f));
    selS[o] = score; selI[o] = idx;
    selB[o * 7 + 0] = xg; selB[o * 7 + 1] = yg; selB[o * 7 + 2] = zg;
    selB[o * 7 + 3] = wg; selB[o * 7 + 4] = lg; selB[o * 7 + 5] = hg;
    selB[o * 7 + 6] = rg;
    float cc = fabsf(cosf(rg)), ss = fabsf(sinf(rg));
    float hx = __fmul_rn(0.5f, __fadd_rn(__fmul_rn(wg, cc), __fmul_rn(lg, ss)));
    float hy = __fmul_rn(0.5f, __fadd_rn(__fmul_rn(wg, ss), __fmul_rn(lg, cc)));
    float x1 = __fsub_rn(xg, hx), y1 = __fsub_rn(yg, hy);
    float x2 = __fadd_rn(xg, hx), y2 = __fadd_rn(yg, hy);
    selBB[o * 4 + 0] = x1; selBB[o * 4 + 1] = y1;
    selBB[o * 4 + 2] = x2; selBB[o * 4 + 3] = y2;
    selA[o] = __fmul_rn(__fsub_rn(x2, x1), __fsub_rn(y2, y1));
}

// suppression bitmask rows: bit j of word w of row i set iff iou(i,j)>0.5 && j>i
__global__ void __launch_bounds__(256) k_iou(const float* __restrict__ selBB,
                                             const float* __restrict__ selA,
                                             uint64_t* __restrict__ maskrows) {
    int b = blockIdx.y;
    int r0 = blockIdx.x * 64;
    __shared__ float sx1[PRE], sy1[PRE], sx2[PRE], sy2[PRE], sar[PRE];
    int t = threadIdx.x;
    for (int i = t; i < PRE; i += 256) {
        const float* p = selBB + ((size_t)b * PRE + i) * 4;
        sx1[i] = p[0]; sy1[i] = p[1]; sx2[i] = p[2]; sy2[i] = p[3];
        sar[i] = selA[(size_t)b * PRE + i];
    }
    __syncthreads();
    int w  = t & 31;
    int rl = t >> 5;
    int jbase = w * 64;
    float rx1[8], ry1[8], rx2[8], ry2[8], rar[8];
    int rows[8];
#pragma unroll
    for (int p = 0; p < 8; p++) {
        int i = r0 + rl * 8 + p;
        rows[p] = i;
        rx1[p] = sx1[i]; ry1[p] = sy1[i]; rx2[p] = sx2[i]; ry2[p] = sy2[i]; rar[p] = sar[i];
    }
    uint64_t bits[8] = {0, 0, 0, 0, 0, 0, 0, 0};
    for (int jj = 0; jj < 64; jj++) {
        int j = jbase + ((jj + w) & 63);
        float xj1 = sx1[j], yj1 = sy1[j], xj2 = sx2[j], yj2 = sy2[j], aj = sar[j];
#pragma unroll
        for (int p = 0; p < 8; p++) {
            float ix = fmaxf(0.f, __fsub_rn(fminf(rx2[p], xj2), fmaxf(rx1[p], xj1)));
            float iy = fmaxf(0.f, __fsub_rn(fminf(ry2[p], yj2), fmaxf(ry1[p], yj1)));
            float inter = __fmul_rn(ix, iy);
            float den = fmaxf(__fsub_rn(__fadd_rn(rar[p], aj), inter), 1e-8f);
            float iou = __fdiv_rn(inter, den);
            if (iou > 0.5f && j > rows[p]) bits[p] |= (1ull << (j - jbase));
        }
    }
#pragma unroll
    for (int p = 0; p < 8; p++)
        maskrows[((size_t)b * PRE + rows[p]) * 32 + w] = bits[p];
}

// sequential greedy NMS (one wave, depth-8 prefetch) + finalize 128 outputs
__global__ void __launch_bounds__(128) k_nms_final(
        const uint64_t* __restrict__ maskrows, const float* __restrict__ selS,
        const uint32_t* __restrict__ selI, const float* __restrict__ selB,
        const uint32_t* __restrict__ counts, const float* __restrict__ dir_preds,
        float* __restrict__ out) {
    int b = blockIdx.x;
    __shared__ int keptIdx[POST];
    __shared__ int keptCount;
    int t = threadIdx.x;
    int Mv = (int)counts[(size_t)b * 64]; if (Mv > PRE) Mv = PRE;
    if (t < 64) {
        uint64_t removed = 0ull;
        int kc = 0;
        const uint64_t* mb = maskrows + (size_t)b * PRE * 32;
        uint64_t pre[8];
#pragma unroll
        for (int d = 0; d < 8; d++)
            pre[d] = (t < 32 && d < Mv) ? mb[(size_t)d * 32 + t] : 0ull;
        for (int i = 0; i < Mv && kc < POST; i++) {
            uint64_t mrow = pre[i & 7];
            int nf = i + 8;
            pre[i & 7] = (t < 32 && nf < Mv) ? mb[(size_t)nf * 32 + t] : 0ull;
            uint64_t rw = __shfl(removed, i >> 6);
            if (!((rw >> (i & 63)) & 1ull)) {
                if (t == 0) keptIdx[kc] = i;
                kc++;
                removed |= mrow;
            }
        }
        if (t == 0) keptCount = kc;
    }
    __syncthreads();
    int kc = keptCount;
    size_t ob = (size_t)b * POST + t;
    float box[7] = {0.f, 0.f, 0.f, 0.f, 0.f, 0.f, 0.f};
    float sc = 0.f, mk = 0.f;
    if (t < kc) {
        int i = keptIdx[t];
        size_t o = (size_t)b * PRE + i;
        float s = selS[o];
        uint32_t idx = selI[o];
        const float* bx = selB + o * 7;
        float d0 = dir_preds[((size_t)b * NN + idx) * 2 + 0];
        float d1 = dir_preds[((size_t)b * NN + idx) * 2 + 1];
        float label = (d1 > d0) ? 1.0f : 0.0f;
        const float period = 3.14159265358979323846f;
        float r = bx[6];
        float dir_rot = __fsub_rn(r, __fmul_rn(floorf(__fdiv_rn(r, period)), period));
        float nr = __fadd_rn(dir_rot, __fmul_rn(period, label));
        float x = bx[0], y = bx[1], z = bx[2];
        bool in_range = (x >= 0.0f) && (y >= -39.68f) && (z >= -5.0f) &&
                        (x <= 69.12f) && (y <= 39.68f) && (z <= 5.0f);
        if (in_range) {
            box[0] = x; box[1] = y; box[2] = z;
            box[3] = bx[3]; box[4] = bx[4]; box[5] = bx[5]; box[6] = nr;
            sc = s; mk = 1.f;
        }
    }
    float* out_b = out;
    float* out_s = out + 7168;
    float* out_l = out + 8192;
    float* out_m = out + 9216;
    for (int c = 0; c < 7; c++) out_b[ob * 7 + c] = box[c];
    out_s[ob] = sc;
    out_l[ob] = 0.f;
    out_m[ob] = mk;
}

extern "C" void kernel_launch(void* const* d_in, const int* in_sizes, int n_in,
                              void* d_out, int out_size, void* d_ws, size_t ws_size,
                              hipStream_t stream) {
    const float* box_preds = (const float*)d_in[0];
    const float* cls_preds = (const float*)d_in[1];
    const float* dir_preds = (const float*)d_in[2];
    const float* anchors   = (const float*)d_in[3];
    float* out = (float*)d_out;
    char* ws = (char*)d_ws;

    float*    scores = (float*)(ws + OFF_SCORES);
    uint32_t* hist   = (uint32_t*)(ws + OFF_HIST);
    uint32_t* counts = (uint32_t*)(ws + OFF_CNT);
    uint32_t* T      = (uint32_t*)(ws + OFF_T);
    uint64_t* cand   = (uint64_t*)(ws + OFF_CAND);
    float*    selS   = (float*)(ws + OFF_SELS);
    uint32_t* selI   = (uint32_t*)(ws + OFF_SELI);
    float*    selB   = (float*)(ws + OFF_SELB);
    float*    selBB  = (float*)(ws + OFF_SBB);
    float*    selA   = (float*)(ws + OFF_SAR);
    uint64_t* maskrows = (uint64_t*)(ws + OFF_MASK);

    int zwords = (int)((SZ_HIST + SZ_CNT + 256) / 4);   // hist + counts + T
    k_zero<<<(zwords + 255) / 256, 256, 0, stream>>>(hist, zwords);

    dim3 gSH(SH_BPB, NB);
    k_scoreshist<<<gSH, 256, 0, stream>>>(cls_preds, scores, hist);
    k_findT<<<NB, 64, 0, stream>>>(hist, T);
    k_compact<<<TOTAL / 512, 256, 0, stream>>>(scores, T, counts, cand);
    dim3 gRank(CAP / 256, NB);
    k_rank_decode<<<gRank, 256, 0, stream>>>(cand, counts, box_preds, anchors,
                                             selS, selI, selB, selBB, selA);
    dim3 gIou(PRE / 64, NB);
    k_iou<<<gIou, 256, 0, stream>>>(selBB, selA, maskrows);
    k_nms_final<<<NB, 128, 0, stream>>>(maskrows, selS, selI, selB, counts,
                                        dir_preds, out);
}

// Round 4
// 214.387 us; speedup vs baseline: 2.9318x; 1.0364x over previous
//
#include <hip/hip_runtime.h>
#include <stdint.h>

#define NB 8
#define NN 107136
#define TOTAL (NB * NN)
#define NPAIR (NN / 2)       // 53568
#define PRE 2048
#define POST 128
#define CAP 4096
#define HBINS 128            // 16-bit key bins restricted to s in [0.5, 1)
#define KEYBASE 0xBF00u
#define SCORE_TH 0.05f
#define SH_BPB 53            // score/hist blocks per batch (53*1024 >= 53568 pairs)

// ---------------- ws layout (bytes) ----------------
static constexpr size_t OFF_SCORES = 0;
static constexpr size_t SZ_SCORES  = (size_t)TOTAL * 4;
static constexpr size_t OFF_HIST   = OFF_SCORES + SZ_SCORES;       // partial hists
static constexpr size_t SZ_HIST    = (size_t)NB * SH_BPB * HBINS * 4;  // 217,088
static constexpr size_t OFF_CNT    = OFF_HIST + SZ_HIST;           // 8 x 64 u32 (256B apart)
static constexpr size_t SZ_CNT     = (size_t)NB * 64 * 4;
static constexpr size_t OFF_T      = OFF_CNT + SZ_CNT;             // 8 u32, pad 256
static constexpr size_t OFF_CAND   = OFF_T + 256;
static constexpr size_t SZ_CAND    = (size_t)NB * CAP * 8;         // 262,144
static constexpr size_t OFF_SELS   = OFF_CAND + SZ_CAND;
static constexpr size_t OFF_SELI   = OFF_SELS + (size_t)NB * PRE * 4;
static constexpr size_t OFF_SELB   = OFF_SELI + (size_t)NB * PRE * 4;
static constexpr size_t OFF_SBB    = OFF_SELB + (size_t)NB * PRE * 7 * 4;
static constexpr size_t OFF_SAR    = OFF_SBB + (size_t)NB * PRE * 4 * 4;
static constexpr size_t OFF_MASK   = OFF_SAR + (size_t)NB * PRE * 4;
static constexpr size_t SZ_MASK    = (size_t)NB * PRE * 32 * 8;    // 4,194,304

// ---------------- kernels ----------------

// fused softmax scores + per-segment partial 128-bin histogram (no global atomics)
__global__ void __launch_bounds__(256) k_scoreshist(const float* __restrict__ cls,
                                                    float* __restrict__ scores,
                                                    uint32_t* __restrict__ hp) {
    int b = blockIdx.y;
    __shared__ uint32_t lh[HBINS];
    int t = threadIdx.x;
    if (t < HBINS) lh[t] = 0u;
    __syncthreads();
    const float4* cp = (const float4*)cls + (size_t)b * NPAIR;
    float2* sp = (float2*)scores + (size_t)b * NPAIR;
#pragma unroll
    for (int k = 0; k < 4; k++) {
        int p = blockIdx.x * 1024 + k * 256 + t;
        if (p < NPAIR) {
            float4 c = cp[p];
            float m0 = fmaxf(c.x, c.y);
            float s0 = __fdiv_rn(expf(__fsub_rn(c.y, m0)),
                                 __fadd_rn(expf(__fsub_rn(c.x, m0)), expf(__fsub_rn(c.y, m0))));
            float m1 = fmaxf(c.z, c.w);
            float s1 = __fdiv_rn(expf(__fsub_rn(c.w, m1)),
                                 __fadd_rn(expf(__fsub_rn(c.z, m1)), expf(__fsub_rn(c.w, m1))));
            sp[p] = make_float2(s0, s1);
            if (s0 >= 0.5f) {
                uint32_t bin = ((__float_as_uint(s0) >> 16) | 0x8000u) - KEYBASE;
                if (bin > 127u) bin = 127u;
                atomicAdd(&lh[bin], 1u);
            }
            if (s1 >= 0.5f) {
                uint32_t bin = ((__float_as_uint(s1) >> 16) | 0x8000u) - KEYBASE;
                if (bin > 127u) bin = 127u;
                atomicAdd(&lh[bin], 1u);
            }
        }
    }
    __syncthreads();
    if (t < HBINS) hp[((size_t)b * SH_BPB + blockIdx.x) * HBINS + t] = lh[t];
}

// per-batch: sum partial hists, find threshold bin; also zero counts + cand (rank pad)
__global__ void __launch_bounds__(256) k_findT(const uint32_t* __restrict__ hp,
                                               uint32_t* __restrict__ Tout,
                                               uint32_t* __restrict__ counts,
                                               uint64_t* __restrict__ cand) {
    int b = blockIdx.x, t = threadIdx.x;
    __shared__ uint32_t hbin[HBINS];
    if (t < HBINS) {
        uint32_t s = 0;
        for (int sg = 0; sg < SH_BPB; sg++)
            s += hp[((size_t)b * SH_BPB + sg) * HBINS + t];
        hbin[t] = s;
    }
    __syncthreads();
    if (t < 64) {
        uint32_t h0 = hbin[2 * t], h1 = hbin[2 * t + 1];
        uint32_t v = h0 + h1;
        for (int off = 1; off < 64; off <<= 1) {
            uint32_t u = __shfl_down(v, off);
            if (t + off >= 64) u = 0u;
            v += u;
        }
        uint32_t total = __shfl(v, 0);
        int c = -1;
        if (v - h0 >= PRE) c = 2 * t + 1;
        else if (v >= PRE) c = 2 * t;
        for (int off = 32; off > 0; off >>= 1) c = max(c, __shfl_xor(c, off));
        if (t == 0) {
            Tout[b] = (total >= PRE && c >= 0) ? (KEYBASE + (uint32_t)c) : 0u;
            counts[(size_t)b * 64] = 0u;
        }
    }
    uint64_t* cb = cand + (size_t)b * CAP;
    for (int i = t; i < CAP; i += 256) cb[i] = 0ull;
}

// compact candidates with key16 >= T; block-aggregated slot reservation; 2 elems/thread
__global__ void __launch_bounds__(256) k_compact(const float* __restrict__ scores,
                                                 const uint32_t* __restrict__ T,
                                                 uint32_t* __restrict__ counts,
                                                 uint64_t* __restrict__ cand) {
    int g2 = blockIdx.x * 256 + threadIdx.x;      // pair index; grid exact
    int lane = threadIdx.x & 63, wid = threadIdx.x >> 6;
    float2 sv = ((const float2*)scores)[g2];
    int e0 = 2 * g2;
    int b = e0 / NN;                              // wave-uniform (NN % 128 == 0)
    uint32_t Tb = T[b];
    uint32_t key0 = __float_as_uint(sv.x) | 0x80000000u;
    uint32_t key1 = __float_as_uint(sv.y) | 0x80000000u;
    bool p0 = (sv.x >= SCORE_TH) && ((key0 >> 16) >= Tb);
    bool p1 = (sv.y >= SCORE_TH) && ((key1 >> 16) >= Tb);
    uint64_t bal0 = __ballot(p0), bal1 = __ballot(p1);
    uint32_t n0 = (uint32_t)__popcll(bal0);
    uint32_t wcnt = n0 + (uint32_t)__popcll(bal1);
    uint64_t below = (1ull << lane) - 1ull;
    uint32_t off0 = (uint32_t)__popcll(bal0 & below);
    uint32_t off1 = n0 + (uint32_t)__popcll(bal1 & below);
    __shared__ uint32_t lcnt[2];
    __shared__ uint32_t gbase[2];
    __shared__ uint32_t wbase[4];
    int b0 = (blockIdx.x * 512) / NN;
    if (threadIdx.x < 2) lcnt[threadIdx.x] = 0u;
    __syncthreads();
    if (lane == 0 && wcnt) wbase[wid] = atomicAdd(&lcnt[b - b0], wcnt);
    __syncthreads();
    if (threadIdx.x < 2 && lcnt[threadIdx.x])
        gbase[threadIdx.x] = atomicAdd(&counts[(size_t)(b0 + threadIdx.x) * 64], lcnt[threadIdx.x]);
    __syncthreads();
    if (p0 | p1) {
        uint32_t base = gbase[b - b0] + wbase[wid];
        if (p0) {
            uint32_t slot = base + off0;
            if (slot < CAP)
                cand[(size_t)b * CAP + slot] =
                    ((uint64_t)key0 << 32) | (uint64_t)(0xFFFFFFFFu - (uint32_t)(e0 - b * NN));
        }
        if (p1) {
            uint32_t slot = base + off1;
            if (slot < CAP)
                cand[(size_t)b * CAP + slot] =
                    ((uint64_t)key1 << 32) | (uint64_t)(0xFFFFFFFFu - (uint32_t)(e0 + 1 - b * NN));
        }
    }
}

// rank via ballot (j-keys in VGPRs, i-key LDS-broadcast, SALU popcount) + fused decode
__global__ void __launch_bounds__(256) k_rankdecode(
        const uint64_t* __restrict__ cand, const uint32_t* __restrict__ counts,
        const float* __restrict__ box_preds, const float* __restrict__ anchors,
        float* __restrict__ selS, uint32_t* __restrict__ selI,
        float* __restrict__ selB, float* __restrict__ selBB, float* __restrict__ selA) {
    int b = blockIdx.y;
    int i0 = blockIdx.x * 256;
    int m = (int)counts[(size_t)b * 64]; if (m > CAP) m = CAP;
    if (i0 >= m) return;
    const uint64_t* cb = cand + (size_t)b * CAP;
    __shared__ uint64_t shI[256];
    __shared__ uint32_t rp[4][4][64];   // [wave][quarter][lane]
    int t = threadIdx.x;
    int lane = t & 63, w = t >> 6;
    shI[t] = cb[i0 + t];
    __syncthreads();
    int sweeps = (m + 2047) / 2048;     // 1 or 2
#pragma unroll
    for (int q = 0; q < 4; q++) {
        uint32_t accq = 0;
        for (int s = 0; s < sweeps; s++) {
            int jb = s * 2048 + w * 512;
            if (jb < m) {               // wave-uniform
                int j0 = jb + lane * 8;
                uint64_t jk[8];
#pragma unroll
                for (int u = 0; u < 8; u++) jk[u] = cb[j0 + u];
                for (int il = 0; il < 64; il++) {
                    uint64_t ik = shI[q * 64 + il];
                    uint32_t p = 0;
#pragma unroll
                    for (int u = 0; u < 8; u++)
                        p += (uint32_t)__popcll(__ballot(jk[u] > ik));
                    if (lane == il) accq += p;
                }
            }
        }
        rp[w][q][lane] = accq;
    }
    __syncthreads();
    int i = i0 + t;
    uint32_t rank = rp[0][w][lane] + rp[1][w][lane] + rp[2][w][lane] + rp[3][w][lane];
    if (i >= m || rank >= PRE) return;
    uint64_t mykey = shI[t];
    size_t o = (size_t)b * PRE + rank;
    uint32_t key = (uint32_t)(mykey >> 32);
    uint32_t idx = 0xFFFFFFFFu - (uint32_t)(mykey & 0xFFFFFFFFull);
    float score = __uint_as_float(key & 0x7FFFFFFFu);
    const float* bp = box_preds + ((size_t)b * NN + idx) * 7;
    const float* an = anchors + ((size_t)b * NN + idx) * 7;
    float xa = an[0], ya = an[1], za = an[2], wa = an[3], la = an[4], ha = an[5], ra = an[6];
    float xt = bp[0], yt = bp[1], zt = bp[2], wt = bp[3], lt = bp[4], ht = bp[5], rt = bp[6];
    float za2  = __fadd_rn(za, __fmul_rn(ha, 0.5f));
    float diag = sqrtf(__fadd_rn(__fmul_rn(la, la), __fmul_rn(wa, wa)));
    float xg = __fadd_rn(__fmul_rn(xt, diag), xa);
    float yg = __fadd_rn(__fmul_rn(yt, diag), ya);
    float zg = __fadd_rn(__fmul_rn(zt, ha), za2);
    float lg = __fmul_rn(expf(lt), la);
    float wg = __fmul_rn(expf(wt), wa);
    float hg = __fmul_rn(expf(ht), ha);
    float rg = __fadd_rn(rt, ra);
    zg = __fsub_rn(zg, __fmul_rn(hg, 0.5f));
    selS[o] = score; selI[o] = idx;
    selB[o * 7 + 0] = xg; selB[o * 7 + 1] = yg; selB[o * 7 + 2] = zg;
    selB[o * 7 + 3] = wg; selB[o * 7 + 4] = lg; selB[o * 7 + 5] = hg;
    selB[o * 7 + 6] = rg;
    float cc = fabsf(cosf(rg)), ss = fabsf(sinf(rg));
    float hx = __fmul_rn(0.5f, __fadd_rn(__fmul_rn(wg, cc), __fmul_rn(lg, ss)));
    float hy = __fmul_rn(0.5f, __fadd_rn(__fmul_rn(wg, ss), __fmul_rn(lg, cc)));
    float x1 = __fsub_rn(xg, hx), y1 = __fsub_rn(yg, hy);
    float x2 = __fadd_rn(xg, hx), y2 = __fadd_rn(yg, hy);
    selBB[o * 4 + 0] = x1; selBB[o * 4 + 1] = y1;
    selBB[o * 4 + 2] = x2; selBB[o * 4 + 3] = y2;
    selA[o] = __fmul_rn(__fsub_rn(x2, x1), __fsub_rn(y2, y1));
}

// suppression bitmask rows; div-free exact compare; 32 rows/block (512 blocks)
__global__ void __launch_bounds__(256) k_iou(const float* __restrict__ selBB,
                                             const float* __restrict__ selA,
                                             uint64_t* __restrict__ maskrows) {
    int b = blockIdx.y;
    int r0 = blockIdx.x * 32;
    __shared__ float sx1[PRE], sy1[PRE], sx2[PRE], sy2[PRE], sar[PRE];  // 40 KiB
    int t = threadIdx.x;
    for (int i = t; i < PRE; i += 256) {
        const float* p = selBB + ((size_t)b * PRE + i) * 4;
        sx1[i] = p[0]; sy1[i] = p[1]; sx2[i] = p[2]; sy2[i] = p[3];
        sar[i] = selA[(size_t)b * PRE + i];
    }
    __syncthreads();
    int w  = t & 31;           // word index
    int rl = t >> 5;           // 0..7, 4 rows each
    int jbase = w * 64;
    float rx1[4], ry1[4], rx2[4], ry2[4], rar[4];
    int rows[4];
#pragma unroll
    for (int p = 0; p < 4; p++) {
        int i = r0 + rl * 4 + p;
        rows[p] = i;
        rx1[p] = sx1[i]; ry1[p] = sy1[i]; rx2[p] = sx2[i]; ry2[p] = sy2[i]; rar[p] = sar[i];
    }
    uint64_t bits[4] = {0, 0, 0, 0};
    for (int jj = 0; jj < 64; jj++) {
        int j = jbase + ((jj + w) & 63);
        float xj1 = sx1[j], yj1 = sy1[j], xj2 = sx2[j], yj2 = sy2[j], aj = sar[j];
#pragma unroll
        for (int p = 0; p < 4; p++) {
            float ix = fmaxf(0.f, __fsub_rn(fminf(rx2[p], xj2), fmaxf(rx1[p], xj1)));
            float iy = fmaxf(0.f, __fsub_rn(fminf(ry2[p], yj2), fmaxf(ry1[p], yj1)));
            float inter = __fmul_rn(ix, iy);
            float den = fmaxf(__fsub_rn(__fadd_rn(rar[p], aj), inter), 1e-8f);
            if (inter > __fmul_rn(0.5f, den) && j > rows[p])
                bits[p] |= (1ull << (j - jbase));
        }
    }
#pragma unroll
    for (int p = 0; p < 4; p++)
        maskrows[((size_t)b * PRE + rows[p]) * 32 + w] = bits[p];
}

// sequential greedy NMS (one wave, depth-8 prefetch) + finalize 128 outputs
__global__ void __launch_bounds__(128) k_nms_final(
        const uint64_t* __restrict__ maskrows, const float* __restrict__ selS,
        const uint32_t* __restrict__ selI, const float* __restrict__ selB,
        const uint32_t* __restrict__ counts, const float* __restrict__ dir_preds,
        float* __restrict__ out) {
    int b = blockIdx.x;
    __shared__ int keptIdx[POST];
    __shared__ int keptCount;
    int t = threadIdx.x;
    int Mv = (int)counts[(size_t)b * 64]; if (Mv > PRE) Mv = PRE;
    if (t < 64) {
        uint64_t removed = 0ull;
        int kc = 0;
        const uint64_t* mb = maskrows + (size_t)b * PRE * 32;
        uint64_t pre[8];
#pragma unroll
        for (int d = 0; d < 8; d++)
            pre[d] = (t < 32 && d < Mv) ? mb[(size_t)d * 32 + t] : 0ull;
        for (int i = 0; i < Mv && kc < POST; i++) {
            uint64_t mrow = pre[i & 7];
            int nf = i + 8;
            pre[i & 7] = (t < 32 && nf < Mv) ? mb[(size_t)nf * 32 + t] : 0ull;
            uint64_t rw = __shfl(removed, i >> 6);
            if (!((rw >> (i & 63)) & 1ull)) {
                if (t == 0) keptIdx[kc] = i;
                kc++;
                removed |= mrow;
            }
        }
        if (t == 0) keptCount = kc;
    }
    __syncthreads();
    int kc = keptCount;
    size_t ob = (size_t)b * POST + t;
    float box[7] = {0.f, 0.f, 0.f, 0.f, 0.f, 0.f, 0.f};
    float sc = 0.f, mk = 0.f;
    if (t < kc) {
        int i = keptIdx[t];
        size_t o = (size_t)b * PRE + i;
        float s = selS[o];
        uint32_t idx = selI[o];
        const float* bx = selB + o * 7;
        float d0 = dir_preds[((size_t)b * NN + idx) * 2 + 0];
        float d1 = dir_preds[((size_t)b * NN + idx) * 2 + 1];
        float label = (d1 > d0) ? 1.0f : 0.0f;
        const float period = 3.14159265358979323846f;
        float r = bx[6];
        float dir_rot = __fsub_rn(r, __fmul_rn(floorf(__fdiv_rn(r, period)), period));
        float nr = __fadd_rn(dir_rot, __fmul_rn(period, label));
        float x = bx[0], y = bx[1], z = bx[2];
        bool in_range = (x >= 0.0f) && (y >= -39.68f) && (z >= -5.0f) &&
                        (x <= 69.12f) && (y <= 39.68f) && (z <= 5.0f);
        if (in_range) {
            box[0] = x; box[1] = y; box[2] = z;
            box[3] = bx[3]; box[4] = bx[4]; box[5] = bx[5]; box[6] = nr;
            sc = s; mk = 1.f;
        }
    }
    float* out_b = out;
    float* out_s = out + 7168;
    float* out_l = out + 8192;
    float* out_m = out + 9216;
    for (int c = 0; c < 7; c++) out_b[ob * 7 + c] = box[c];
    out_s[ob] = sc;
    out_l[ob] = 0.f;
    out_m[ob] = mk;
}

extern "C" void kernel_launch(void* const* d_in, const int* in_sizes, int n_in,
                              void* d_out, int out_size, void* d_ws, size_t ws_size,
                              hipStream_t stream) {
    const float* box_preds = (const float*)d_in[0];
    const float* cls_preds = (const float*)d_in[1];
    const float* dir_preds = (const float*)d_in[2];
    const float* anchors   = (const float*)d_in[3];
    float* out = (float*)d_out;
    char* ws = (char*)d_ws;

    float*    scores = (float*)(ws + OFF_SCORES);
    uint32_t* hp     = (uint32_t*)(ws + OFF_HIST);
    uint32_t* counts = (uint32_t*)(ws + OFF_CNT);
    uint32_t* T      = (uint32_t*)(ws + OFF_T);
    uint64_t* cand   = (uint64_t*)(ws + OFF_CAND);
    float*    selS   = (float*)(ws + OFF_SELS);
    uint32_t* selI   = (uint32_t*)(ws + OFF_SELI);
    float*    selB   = (float*)(ws + OFF_SELB);
    float*    selBB  = (float*)(ws + OFF_SBB);
    float*    selA   = (float*)(ws + OFF_SAR);
    uint64_t* maskrows = (uint64_t*)(ws + OFF_MASK);

    dim3 gSH(SH_BPB, NB);
    k_scoreshist<<<gSH, 256, 0, stream>>>(cls_preds, scores, hp);
    k_findT<<<NB, 256, 0, stream>>>(hp, T, counts, cand);
    k_compact<<<TOTAL / 512, 256, 0, stream>>>(scores, T, counts, cand);
    dim3 gRank(CAP / 256, NB);
    k_rankdecode<<<gRank, 256, 0, stream>>>(cand, counts, box_preds, anchors,
                                            selS, selI, selB, selBB, selA);
    dim3 gIou(PRE / 32, NB);
    k_iou<<<gIou, 256, 0, stream>>>(selBB, selA, maskrows);
    k_nms_final<<<NB, 128, 0, stream>>>(maskrows, selS, selI, selB, counts,
                                        dir_preds, out);
}